// Round 1
// 292.395 us; speedup vs baseline: 1.0344x; 1.0344x over previous
//
#include <hip/hip_runtime.h>

typedef __bf16 bf16_t;
typedef __bf16 bf16x2 __attribute__((ext_vector_type(2)));
typedef __bf16 bf16x4 __attribute__((ext_vector_type(4)));
typedef __bf16 bf16x8 __attribute__((ext_vector_type(8)));
typedef float floatx4 __attribute__((ext_vector_type(4)));

// async 16B/lane global->LDS (bf16 operands only). Dest = wave-uniform base + lane*16.
__device__ __forceinline__ void gll16(const void* g, void* l) {
  __builtin_amdgcn_global_load_lds(
      (const __attribute__((address_space(1))) void*)g,
      (__attribute__((address_space(3))) void*)l, 16, 0, 0);
}

__device__ __forceinline__ bf16x8 cvt8(const float4 a, const float4 b) {
  bf16x8 v;
  v[0] = (bf16_t)a.x; v[1] = (bf16_t)a.y; v[2] = (bf16_t)a.z; v[3] = (bf16_t)a.w;
  v[4] = (bf16_t)b.x; v[5] = (bf16_t)b.y; v[6] = (bf16_t)b.z; v[7] = (bf16_t)b.w;
  return v;
}

// ---------------------------------------------------------------------------
// fp32 -> bf16 elementwise, 8 elems/thread, fully coalesced.
// ---------------------------------------------------------------------------
__global__ __launch_bounds__(256)
void cvt_f32_bf16(const float* __restrict__ src, bf16_t* __restrict__ dst, int n8)
{
  const int i = blockIdx.x * 256 + threadIdx.x;
  if (i < n8) {
    const float4 a = ((const float4*)src)[2 * i];
    const float4 b = ((const float4*)src)[2 * i + 1];
    *(bf16x8*)(dst + (size_t)i * 8) = cvt8(a, b);
  }
}

// ---------------------------------------------------------------------------
// GEMM: C[M,Nf] = A[M,K] * W[Nf,K]^T (+bias), fp32 accum, bf16 MFMA.
// Round-11 change: T1 XCD-aware block swizzle (grid must be %8==0; both are).
// ---------------------------------------------------------------------------
template<bool A32, bool W32, bool C32>
__global__ __launch_bounds__(256, 2)
void gemm_bt(const void* __restrict__ Av, const void* __restrict__ Wv,
             const float* __restrict__ bias, void* __restrict__ Cv,
             int M, int Nf, int K, int lda)
{
  __shared__ __align__(16) bf16_t lA[128 * 32];
  __shared__ __align__(16) bf16_t lB[128 * 32];

  const int tid  = threadIdx.x;
  const int wave = tid >> 6;
  const int lane = tid & 63;
  const int q    = lane >> 4;
  const int ln   = lane & 15;
  const int wm   = wave >> 1, wn = wave & 1;

  // XCD swizzle: consecutive work-ids stay on one XCD's L2.
  const int nwg = gridDim.x;
  const int bid = (blockIdx.x & 7) * (nwg >> 3) + (blockIdx.x >> 3);

  const int mtiles = M >> 7;
  const int mt = bid % mtiles;
  const int nt = bid / mtiles;
  const int m0 = mt << 7, n0 = nt << 7;

  floatx4 acc[4][4] = {};

  for (int k0 = 0; k0 < K; k0 += 32) {
    if constexpr (A32) {
      const float* Af = (const float*)Av;
#pragma unroll
      for (int sub = 0; sub < 2; ++sub) {
        const int r  = sub * 64 + (tid >> 2);
        const int c8 = tid & 3;
        const float* s = Af + (size_t)(m0 + r) * lda + k0 + c8 * 8;
        const float4 f0 = *(const float4*)s;
        const float4 f1 = *(const float4*)(s + 4);
        *(bf16x8*)(lA + r * 32 + (c8 ^ ((r >> 1) & 3)) * 8) = cvt8(f0, f1);
      }
    } else {
      const bf16_t* Ab = (const bf16_t*)Av;
#pragma unroll
      for (int half = 0; half < 2; ++half) {
        const int rbase = half * 64 + wave * 16;
        const int r  = rbase + (lane >> 2);
        const int gc = (lane & 3) ^ ((r >> 1) & 3);
        gll16(Ab + (size_t)(m0 + r) * lda + k0 + gc * 8, lA + rbase * 32);
      }
    }
    if constexpr (W32) {
      const float* Wf = (const float*)Wv;
#pragma unroll
      for (int sub = 0; sub < 2; ++sub) {
        const int r  = sub * 64 + (tid >> 2);
        const int c8 = tid & 3;
        const float* s = Wf + (size_t)(n0 + r) * K + k0 + c8 * 8;
        const float4 f0 = *(const float4*)s;
        const float4 f1 = *(const float4*)(s + 4);
        *(bf16x8*)(lB + r * 32 + (c8 ^ ((r >> 1) & 3)) * 8) = cvt8(f0, f1);
      }
    } else {
      const bf16_t* Wb = (const bf16_t*)Wv;
#pragma unroll
      for (int half = 0; half < 2; ++half) {
        const int rbase = half * 64 + wave * 16;
        const int r  = rbase + (lane >> 2);
        const int gc = (lane & 3) ^ ((r >> 1) & 3);
        gll16(Wb + (size_t)(n0 + r) * K + k0 + gc * 8, lB + rbase * 32);
      }
    }
    __syncthreads();

    bf16x8 af[4], bfr[4];
#pragma unroll
    for (int i = 0; i < 4; ++i) {
      const int r = wm * 64 + i * 16 + ln;
      af[i] = *(const bf16x8*)(lA + r * 32 + (q ^ ((r >> 1) & 3)) * 8);
    }
#pragma unroll
    for (int j = 0; j < 4; ++j) {
      const int r = wn * 64 + j * 16 + ln;
      bfr[j] = *(const bf16x8*)(lB + r * 32 + (q ^ ((r >> 1) & 3)) * 8);
    }
#pragma unroll
    for (int i = 0; i < 4; ++i)
#pragma unroll
      for (int j = 0; j < 4; ++j)
        acc[i][j] = __builtin_amdgcn_mfma_f32_16x16x32_bf16(af[i], bfr[j], acc[i][j], 0, 0, 0);
    __syncthreads();
  }

  // epilogue: C/D layout col=lane&15, row=(lane>>4)*4+reg
#pragma unroll
  for (int j = 0; j < 4; ++j) {
    const int col = n0 + wn * 64 + j * 16 + ln;
    const float bv = bias ? bias[col] : 0.0f;
#pragma unroll
    for (int i = 0; i < 4; ++i) {
      const int row = m0 + wm * 64 + i * 16 + q * 4;
#pragma unroll
      for (int r = 0; r < 4; ++r) {
        const float val = acc[i][j][r] + bv;
        if constexpr (C32)
          ((float*)Cv)[(size_t)(row + r) * Nf + col] = val;
        else
          ((bf16_t*)Cv)[(size_t)(row + r) * Nf + col] = (bf16_t)val;
      }
    }
  }
}

// ---------------------------------------------------------------------------
// Attention, in-place on bf16 qkv. Round-11: latency attack.
//  (1) Software pipeline: lK double-buffered (gll16 prefetch of K[jt+1] and
//      V[jt+1]->regs issued during S^T of tile jt) -> barrier drain hidden
//      under ~1 compute phase instead of fully exposed.
//  (2) 2 barriers/iter (was 3): V scatter moved after the iteration-top
//      barrier, so PV-done and staging-ready share one barrier.
//  (3) lP: stride 136 pad -> stride 128 + chunk-XOR ^(m&7) (same bank
//      spread, -2.8KB). LDS total = 32+16+32 = 80 KiB -> still 2 blocks/CU.
//  (4) T1 XCD swizzle: 16 q-tiles x 8 heads per XCD -> K/V set = 4MB = L2.
//  (5) T5 setprio(1) around MFMA clusters.
// ---------------------------------------------------------------------------
__global__ __launch_bounds__(256, 2)
void attn_kernel(bf16_t* __restrict__ qkv)
{
  __shared__ __align__(16) bf16_t lK[2][128 * 64]; // K tile dbuf [128 tok][64 d]
  __shared__ __align__(16) bf16_t lVT[64 * 128];   // V^T [64 d][128 tok], chunk^(d&7)
  __shared__ __align__(16) bf16_t lP[128 * 128];   // P [m][tok], chunk^(m&7); head = Q staging

  const int tid  = threadIdx.x;
  const int wave = tid >> 6;
  const int lane = tid & 63;
  const int q  = lane >> 4;
  const int ln = lane & 15;
  const int wm = wave >> 1, wn = wave & 1;

  // XCD swizzle: hw%8 = XCD; give each XCD 128 consecutive work-ids
  // (= all 16 q-tiles of 8 heads -> K/V working set 4MB = one L2).
  const int hw = blockIdx.x;
  const int w  = (hw & 7) * 128 + (hw >> 3);
  const int qt = w & 15;
  const int h  = (w >> 4) & 15;
  const int b  = w >> 8;

  bf16_t* Qbase = qkv + (size_t)(b * 2048 + qt * 128) * 3072 + h * 64;  // also O dest
  const bf16_t* Kbase = qkv + (size_t)(b * 2048) * 3072 + 1024 + h * 64;
  const bf16_t* Vbase = qkv + (size_t)(b * 2048) * 3072 + 2048 + h * 64;

  // ---- prologue: stage Q into lP head (flat [128][64], chunk^(r&7)) + K[0]
#pragma unroll
  for (int t = 0; t < 4; ++t) {
    const int rbase = t * 32 + wave * 8;
    const int r  = rbase + (lane >> 3);
    const int gc = (lane & 7) ^ (r & 7);
    gll16(Qbase + (size_t)r * 3072 + gc * 8, lP + rbase * 64);
    gll16(Kbase + (size_t)r * 3072 + gc * 8, lK[0] + rbase * 64);
  }
  __syncthreads();

  bf16x8 qf[4][2];  // Q[m][d] fragments; used as MFMA B-operand (Q^T[d][m])
#pragma unroll
  for (int i = 0; i < 4; ++i) {
    const int r = wm * 64 + i * 16 + ln;
#pragma unroll
    for (int kt = 0; kt < 2; ++kt) {
      const int c = (kt * 4 + q) ^ (r & 7);
      qf[i][kt] = *(const bf16x8*)(lP + r * 64 + c * 8);
    }
  }
  // (no barrier needed here: iter-0's top barrier orders qf reads vs lP reuse)

  // V[0] into regs (token pair 2*lane, 2*lane+1; d-chunks wave + it*4)
  bf16x8 vcur[2][2], vnxt[2][2];
#pragma unroll
  for (int it = 0; it < 2; ++it) {
    const bf16_t* src = Vbase + (size_t)(2 * lane) * 3072 + (wave + it * 4) * 8;
    vcur[it][0] = *(const bf16x8*)src;
    vcur[it][1] = *(const bf16x8*)(src + 3072);
  }

  floatx4 accO[4][2] = {};
  floatx4 accS[4] = {};  // row sums via ones-column MFMA

  bf16x8 ones;
#pragma unroll
  for (int j = 0; j < 8; ++j) ones[j] = (bf16_t)1.0f;

  for (int jt = 0; jt < 16; ++jt) {
    const bf16_t* lKc = lK[jt & 1];
    bf16_t*       lKn = lK[(jt & 1) ^ 1];

    // syncA: prev-iter PV reads of lVT/lP done; lK[cur] gll16 + vcur loads
    // (issued one phase ago) complete here via the barrier's vmcnt drain.
    __syncthreads();

    // scatter vcur -> lVT[d][tok], tok-chunk ch = (tok>>3)^(d&7)
#pragma unroll
    for (int it = 0; it < 2; ++it) {
      const int c = wave + it * 4;
#pragma unroll
      for (int j = 0; j < 8; ++j) {
        const int d  = c * 8 + j;
        const int ch = (lane >> 2) ^ (d & 7);
        bf16x2 pr;
        pr[0] = vcur[it][0][j];
        pr[1] = vcur[it][1][j];
        *(bf16x2*)(lVT + d * 128 + ch * 8 + ((2 * lane) & 7)) = pr;
      }
    }

    // K fragments from current buffer
    bf16x8 kf[4][2];
#pragma unroll
    for (int n = 0; n < 4; ++n) {
      const int r = wn * 64 + n * 16 + ln;
#pragma unroll
      for (int kt = 0; kt < 2; ++kt) {
        const int c = (kt * 4 + q) ^ (r & 7);
        kf[n][kt] = *(const bf16x8*)(lKc + r * 64 + c * 8);
      }
    }

    // ---- prefetch tile jt+1: K -> lK[nxt] (async DMA), V -> regs.
    // Drained at syncB, after the S^T phase -> latency mostly hidden.
    if (jt < 15) {
      const int j0n = (jt + 1) * 128;
#pragma unroll
      for (int t = 0; t < 4; ++t) {
        const int rbase = t * 32 + wave * 8;
        const int r  = rbase + (lane >> 3);
        const int gc = (lane & 7) ^ (r & 7);
        gll16(Kbase + (size_t)(j0n + r) * 3072 + gc * 8, lKn + rbase * 64);
      }
#pragma unroll
      for (int it = 0; it < 2; ++it) {
        const bf16_t* src = Vbase + (size_t)(j0n + 2 * lane) * 3072 + (wave + it * 4) * 8;
        vnxt[it][0] = *(const bf16x8*)src;
        vnxt[it][1] = *(const bf16x8*)(src + 3072);
      }
    }

    // ---- S^T = K Q^T  (wave: toks [wn*64,+64) x m [wm*64,+64))
    __builtin_amdgcn_s_setprio(1);
#pragma unroll
    for (int i = 0; i < 4; ++i) {      // tok-tile
#pragma unroll
      for (int n = 0; n < 4; ++n) {    // m-tile
        floatx4 st = {0.0f, 0.0f, 0.0f, 0.0f};
        st = __builtin_amdgcn_mfma_f32_16x16x32_bf16(kf[i][0], qf[n][0], st, 0, 0, 0);
        st = __builtin_amdgcn_mfma_f32_16x16x32_bf16(kf[i][1], qf[n][1], st, 0, 0, 0);
        // lane holds S^T[tok = wn*64+i*16+q*4+r][m = wm*64+n*16+ln], r=0..3
        bf16x4 pk;
#pragma unroll
        for (int r = 0; r < 4; ++r)
          pk[r] = (bf16_t)__builtin_amdgcn_exp2f(st[r] * 0.04508422f);
        const int m    = wm * 64 + n * 16 + ln;
        const int tok0 = wn * 64 + i * 16 + q * 4;
        *(bf16x4*)(lP + m * 128 + (((tok0 >> 3) ^ (m & 7)) << 3) + (tok0 & 7)) = pk;
      }
    }
    __builtin_amdgcn_s_setprio(0);

    // syncB: lP + lVT visible to all waves (also drains prefetches -- mostly
    // complete after the S^T phase above).
    __syncthreads();

    // ---- O += P * V ; rowsum += P * 1  (wave: rows [wm*64,+64) x d [wn*32,+32))
    __builtin_amdgcn_s_setprio(1);
#pragma unroll
    for (int ks = 0; ks < 4; ++ks) {
      bf16x8 bv[2];
#pragma unroll
      for (int n = 0; n < 2; ++n) {
        const int d  = wn * 32 + n * 16 + ln;
        const int cc = (ks * 4 + q) ^ (d & 7);
        bv[n] = *(const bf16x8*)(lVT + d * 128 + cc * 8);
      }
#pragma unroll
      for (int i = 0; i < 4; ++i) {
        const int m = wm * 64 + i * 16 + ln;
        const bf16x8 ap = *(const bf16x8*)(lP + m * 128 + (((ks * 4 + q) ^ (m & 7)) << 3));
        accO[i][0] = __builtin_amdgcn_mfma_f32_16x16x32_bf16(ap, bv[0], accO[i][0], 0, 0, 0);
        accO[i][1] = __builtin_amdgcn_mfma_f32_16x16x32_bf16(ap, bv[1], accO[i][1], 0, 0, 0);
        accS[i]    = __builtin_amdgcn_mfma_f32_16x16x32_bf16(ap, ones,  accS[i],    0, 0, 0);
      }
    }
    __builtin_amdgcn_s_setprio(0);

    if (jt < 15) {
#pragma unroll
      for (int it = 0; it < 2; ++it) {
        vcur[it][0] = vnxt[it][0];
        vcur[it][1] = vnxt[it][1];
      }
    }
  }

  // ---- normalize and store O over the Q slot.
#pragma unroll
  for (int i = 0; i < 4; ++i) {
#pragma unroll
    for (int r = 0; r < 4; ++r) {
      const int row = wm * 64 + i * 16 + q * 4 + r;
      const float rcp = 1.0f / fmaxf(accS[i][r], 1e-20f);
#pragma unroll
      for (int n = 0; n < 2; ++n) {
        const int col = wn * 32 + n * 16 + ln;
        Qbase[(size_t)row * 3072 + col] = (bf16_t)(accO[i][n][r] * rcp);
      }
    }
  }
}

// ---------------------------------------------------------------------------
extern "C" void kernel_launch(void* const* d_in, const int* in_sizes, int n_in,
                              void* d_out, int out_size, void* d_ws, size_t ws_size,
                              hipStream_t stream)
{
  const float* x     = (const float*)d_in[0];  // [4,2048,1024] fp32
  const float* w_qkv = (const float*)d_in[1];  // [3072,1024]   fp32
  const float* w_out = (const float*)d_in[2];  // [1024,1024]   fp32
  const float* b_out = (const float*)d_in[3];  // [1024]        fp32
  float* out = (float*)d_out;                  // [4,2048,1024] fp32

  // ws layout (75.5 MB total)
  bf16_t* qkv    = (bf16_t*)d_ws;                       // 8192*3072
  bf16_t* xb     = qkv    + (size_t)8192 * 3072;        // 8192*1024
  bf16_t* wqkvb  = xb     + (size_t)8192 * 1024;        // 3072*1024
  bf16_t* woutb  = wqkvb  + (size_t)3072 * 1024;        // 1024*1024

  // 0) pre-convert fp32 operands to bf16 (memory-bound, ~12 us)
  cvt_f32_bf16<<<dim3(4096), dim3(256), 0, stream>>>(x,     xb,    8192 * 1024 / 8);
  cvt_f32_bf16<<<dim3(1536), dim3(256), 0, stream>>>(w_qkv, wqkvb, 3072 * 1024 / 8);
  cvt_f32_bf16<<<dim3(512),  dim3(256), 0, stream>>>(w_out, woutb, 1024 * 1024 / 8);

  // 1) qkv = xb @ wqkvb^T   (all-bf16 gll16 path)
  gemm_bt<false, false, false><<<dim3(64 * 24), dim3(256), 0, stream>>>(
      xb, wqkvb, nullptr, qkv, 8192, 3072, 1024, 1024);
  // 2) attention in-place: O overwrites the Q slot of qkv (bf16)
  attn_kernel<<<dim3(1024), dim3(256), 0, stream>>>(qkv);
  // 3) out = O @ woutb^T + b_out  (bf16 in, fp32 out; O strided at lda=3072)
  gemm_bt<false, false, true><<<dim3(64 * 8), dim3(256), 0, stream>>>(
      qkv, woutb, b_out, out, 8192, 1024, 1024, 3072);
}

// Round 3
// 276.159 us; speedup vs baseline: 1.0952x; 1.0588x over previous
//
#include <hip/hip_runtime.h>

typedef __bf16 bf16_t;
typedef __bf16 bf16x2 __attribute__((ext_vector_type(2)));
typedef __bf16 bf16x4 __attribute__((ext_vector_type(4)));
typedef __bf16 bf16x8 __attribute__((ext_vector_type(8)));
typedef float floatx4 __attribute__((ext_vector_type(4)));

// async 16B/lane global->LDS (bf16 operands only). Dest = wave-uniform base + lane*16.
__device__ __forceinline__ void gll16(const void* g, void* l) {
  __builtin_amdgcn_global_load_lds(
      (const __attribute__((address_space(1))) void*)g,
      (__attribute__((address_space(3))) void*)l, 16, 0, 0);
}

__device__ __forceinline__ bf16x8 cvt8(const float4 a, const float4 b) {
  bf16x8 v;
  v[0] = (bf16_t)a.x; v[1] = (bf16_t)a.y; v[2] = (bf16_t)a.z; v[3] = (bf16_t)a.w;
  v[4] = (bf16_t)b.x; v[5] = (bf16_t)b.y; v[6] = (bf16_t)b.z; v[7] = (bf16_t)b.w;
  return v;
}

// ---------------------------------------------------------------------------
// fp32 -> bf16 elementwise, 8 elems/thread, fully coalesced.
// ---------------------------------------------------------------------------
__global__ __launch_bounds__(256)
void cvt_f32_bf16(const float* __restrict__ src, bf16_t* __restrict__ dst, int n8)
{
  const int i = blockIdx.x * 256 + threadIdx.x;
  if (i < n8) {
    const float4 a = ((const float4*)src)[2 * i];
    const float4 b = ((const float4*)src)[2 * i + 1];
    *(bf16x8*)(dst + (size_t)i * 8) = cvt8(a, b);
  }
}

// ---------------------------------------------------------------------------
// GEMM: C[M,Nf] = A[M,K] * W[Nf,K]^T (+bias), fp32 accum, bf16 MFMA.
// Round-12: (a) XCD mapping = mt-chunked (each XCD owns 8 mt rows for all nt
//           -> per-XCD A working set 2MB = L2-resident; r11's nt-chunk gave
//           each XCD ALL of A = 16MB, thrashing).
//           (b) qscale epilogue fold: cols < qcols scaled by qscale in f32
//           (softmax scale*log2e folded into Q at zero attn-side cost).
// ---------------------------------------------------------------------------
template<bool A32, bool W32, bool C32>
__global__ __launch_bounds__(256, 2)
void gemm_bt(const void* __restrict__ Av, const void* __restrict__ Wv,
             const float* __restrict__ bias, void* __restrict__ Cv,
             int M, int Nf, int K, int lda, int qcols, float qscale)
{
  __shared__ __align__(16) bf16_t lA[128 * 32];
  __shared__ __align__(16) bf16_t lB[128 * 32];

  const int tid  = threadIdx.x;
  const int wave = tid >> 6;
  const int lane = tid & 63;
  const int q    = lane >> 4;
  const int ln   = lane & 15;
  const int wm   = wave >> 1, wn = wave & 1;

  // XCD mapping: x = hw XCD (blockIdx%8). XCD x owns mt in [x*8, x*8+8),
  // iterating nt-major inside. Requires mtiles==64 (M==8192): holds here.
  const int x     = blockIdx.x & 7;
  const int local = blockIdx.x >> 3;
  const int mt = x * 8 + (local & 7);
  const int nt = local >> 3;
  const int m0 = mt << 7, n0 = nt << 7;

  floatx4 acc[4][4] = {};

  for (int k0 = 0; k0 < K; k0 += 32) {
    if constexpr (A32) {
      const float* Af = (const float*)Av;
#pragma unroll
      for (int sub = 0; sub < 2; ++sub) {
        const int r  = sub * 64 + (tid >> 2);
        const int c8 = tid & 3;
        const float* s = Af + (size_t)(m0 + r) * lda + k0 + c8 * 8;
        const float4 f0 = *(const float4*)s;
        const float4 f1 = *(const float4*)(s + 4);
        *(bf16x8*)(lA + r * 32 + (c8 ^ ((r >> 1) & 3)) * 8) = cvt8(f0, f1);
      }
    } else {
      const bf16_t* Ab = (const bf16_t*)Av;
#pragma unroll
      for (int half = 0; half < 2; ++half) {
        const int rbase = half * 64 + wave * 16;
        const int r  = rbase + (lane >> 2);
        const int gc = (lane & 3) ^ ((r >> 1) & 3);
        gll16(Ab + (size_t)(m0 + r) * lda + k0 + gc * 8, lA + rbase * 32);
      }
    }
    if constexpr (W32) {
      const float* Wf = (const float*)Wv;
#pragma unroll
      for (int sub = 0; sub < 2; ++sub) {
        const int r  = sub * 64 + (tid >> 2);
        const int c8 = tid & 3;
        const float* s = Wf + (size_t)(n0 + r) * K + k0 + c8 * 8;
        const float4 f0 = *(const float4*)s;
        const float4 f1 = *(const float4*)(s + 4);
        *(bf16x8*)(lB + r * 32 + (c8 ^ ((r >> 1) & 3)) * 8) = cvt8(f0, f1);
      }
    } else {
      const bf16_t* Wb = (const bf16_t*)Wv;
#pragma unroll
      for (int half = 0; half < 2; ++half) {
        const int rbase = half * 64 + wave * 16;
        const int r  = rbase + (lane >> 2);
        const int gc = (lane & 3) ^ ((r >> 1) & 3);
        gll16(Wb + (size_t)(n0 + r) * K + k0 + gc * 8, lB + rbase * 32);
      }
    }
    __syncthreads();

    bf16x8 af[4], bfr[4];
#pragma unroll
    for (int i = 0; i < 4; ++i) {
      const int r = wm * 64 + i * 16 + ln;
      af[i] = *(const bf16x8*)(lA + r * 32 + (q ^ ((r >> 1) & 3)) * 8);
    }
#pragma unroll
    for (int j = 0; j < 4; ++j) {
      const int r = wn * 64 + j * 16 + ln;
      bfr[j] = *(const bf16x8*)(lB + r * 32 + (q ^ ((r >> 1) & 3)) * 8);
    }
#pragma unroll
    for (int i = 0; i < 4; ++i)
#pragma unroll
      for (int j = 0; j < 4; ++j)
        acc[i][j] = __builtin_amdgcn_mfma_f32_16x16x32_bf16(af[i], bfr[j], acc[i][j], 0, 0, 0);
    __syncthreads();
  }

  // epilogue: C/D layout col=lane&15, row=(lane>>4)*4+reg
#pragma unroll
  for (int j = 0; j < 4; ++j) {
    const int col = n0 + wn * 64 + j * 16 + ln;
    const float bv = bias ? bias[col] : 0.0f;
    const float sc = (col < qcols) ? qscale : 1.0f;
#pragma unroll
    for (int i = 0; i < 4; ++i) {
      const int row = m0 + wm * 64 + i * 16 + q * 4;
#pragma unroll
      for (int r = 0; r < 4; ++r) {
        const float val = acc[i][j][r] * sc + bv;
        if constexpr (C32)
          ((float*)Cv)[(size_t)(row + r) * Nf + col] = val;
        else
          ((bf16_t*)Cv)[(size_t)(row + r) * Nf + col] = (bf16_t)val;
      }
    }
  }
}

// ---------------------------------------------------------------------------
// Attention, in-place on bf16 qkv (Q pre-scaled by softmax scale * log2e).
// Round-12 changes:
//  (1) PV m-split: each wave owns 32 m-rows x all 64 d (was 64m x 32d with
//      accS rowsum computed TWICE per m-row). MFMA/wave/iter 80 -> 72,
//      ap reads 16 -> 8 b128 (bv 8 -> 16; net LDS equal), -8 VGPR.
//  (2) exp2 direct (no per-tile scale mul; scale folded into Q by GEMM1).
// ---------------------------------------------------------------------------
__global__ __launch_bounds__(256, 2)
void attn_kernel(bf16_t* __restrict__ qkv)
{
  __shared__ __align__(16) bf16_t lK[2][128 * 64]; // K tile dbuf [128 tok][64 d]
  __shared__ __align__(16) bf16_t lVT[64 * 128];   // V^T [64 d][128 tok], chunk^(d&7)
  __shared__ __align__(16) bf16_t lP[128 * 128];   // P [m][tok], chunk^(m&7); head = Q staging

  const int tid  = threadIdx.x;
  const int wave = tid >> 6;
  const int lane = tid & 63;
  const int q  = lane >> 4;
  const int ln = lane & 15;
  const int wm = wave >> 1, wn = wave & 1;

  // XCD swizzle: hw%8 = XCD; give each XCD 128 consecutive work-ids
  // (= all 16 q-tiles of 8 heads -> K/V working set 4MB = one L2).
  const int hw = blockIdx.x;
  const int w  = (hw & 7) * 128 + (hw >> 3);
  const int qt = w & 15;
  const int h  = (w >> 4) & 15;
  const int b  = w >> 8;

  bf16_t* Qbase = qkv + (size_t)(b * 2048 + qt * 128) * 3072 + h * 64;  // also O dest
  const bf16_t* Kbase = qkv + (size_t)(b * 2048) * 3072 + 1024 + h * 64;
  const bf16_t* Vbase = qkv + (size_t)(b * 2048) * 3072 + 2048 + h * 64;

  // ---- prologue: stage Q into lP head (flat [128][64], chunk^(r&7)) + K[0]
#pragma unroll
  for (int t = 0; t < 4; ++t) {
    const int rbase = t * 32 + wave * 8;
    const int r  = rbase + (lane >> 3);
    const int gc = (lane & 7) ^ (r & 7);
    gll16(Qbase + (size_t)r * 3072 + gc * 8, lP + rbase * 64);
    gll16(Kbase + (size_t)r * 3072 + gc * 8, lK[0] + rbase * 64);
  }
  __syncthreads();

  bf16x8 qf[4][2];  // Q[m][d] fragments; used as MFMA B-operand (Q^T[d][m])
#pragma unroll
  for (int i = 0; i < 4; ++i) {
    const int r = wm * 64 + i * 16 + ln;
#pragma unroll
    for (int kt = 0; kt < 2; ++kt) {
      const int c = (kt * 4 + q) ^ (r & 7);
      qf[i][kt] = *(const bf16x8*)(lP + r * 64 + c * 8);
    }
  }
  // (no barrier needed here: iter-0's top barrier orders qf reads vs lP reuse)

  // V[0] into regs (token pair 2*lane, 2*lane+1; d-chunks wave + it*4)
  bf16x8 vcur[2][2], vnxt[2][2];
#pragma unroll
  for (int it = 0; it < 2; ++it) {
    const bf16_t* src = Vbase + (size_t)(2 * lane) * 3072 + (wave + it * 4) * 8;
    vcur[it][0] = *(const bf16x8*)src;
    vcur[it][1] = *(const bf16x8*)(src + 3072);
  }

  floatx4 accO[2][4] = {};  // [m-tile i][d-tile n]
  floatx4 accS[2] = {};     // row sums via ones-column MFMA (deduped: 1x per m-row)

  bf16x8 ones;
#pragma unroll
  for (int j = 0; j < 8; ++j) ones[j] = (bf16_t)1.0f;

  for (int jt = 0; jt < 16; ++jt) {
    const bf16_t* lKc = lK[jt & 1];
    bf16_t*       lKn = lK[(jt & 1) ^ 1];

    // syncA: prev-iter PV reads of lVT/lP done; lK[cur] gll16 + vcur loads
    // (issued one phase ago) complete here via the barrier's vmcnt drain.
    __syncthreads();

    // scatter vcur -> lVT[d][tok], tok-chunk ch = (tok>>3)^(d&7)
#pragma unroll
    for (int it = 0; it < 2; ++it) {
      const int c = wave + it * 4;
#pragma unroll
      for (int j = 0; j < 8; ++j) {
        const int d  = c * 8 + j;
        const int ch = (lane >> 2) ^ (d & 7);
        bf16x2 pr;
        pr[0] = vcur[it][0][j];
        pr[1] = vcur[it][1][j];
        *(bf16x2*)(lVT + d * 128 + ch * 8 + ((2 * lane) & 7)) = pr;
      }
    }

    // K fragments from current buffer
    bf16x8 kf[4][2];
#pragma unroll
    for (int n = 0; n < 4; ++n) {
      const int r = wn * 64 + n * 16 + ln;
#pragma unroll
      for (int kt = 0; kt < 2; ++kt) {
        const int c = (kt * 4 + q) ^ (r & 7);
        kf[n][kt] = *(const bf16x8*)(lKc + r * 64 + c * 8);
      }
    }

    // ---- prefetch tile jt+1: K -> lK[nxt] (async DMA), V -> regs.
    // Drained at syncB, after the S^T phase -> latency mostly hidden.
    if (jt < 15) {
      const int j0n = (jt + 1) * 128;
#pragma unroll
      for (int t = 0; t < 4; ++t) {
        const int rbase = t * 32 + wave * 8;
        const int r  = rbase + (lane >> 3);
        const int gc = (lane & 7) ^ (r & 7);
        gll16(Kbase + (size_t)(j0n + r) * 3072 + gc * 8, lKn + rbase * 64);
      }
#pragma unroll
      for (int it = 0; it < 2; ++it) {
        const bf16_t* src = Vbase + (size_t)(j0n + 2 * lane) * 3072 + (wave + it * 4) * 8;
        vnxt[it][0] = *(const bf16x8*)src;
        vnxt[it][1] = *(const bf16x8*)(src + 3072);
      }
    }

    // ---- S^T = K Q^T  (wave: toks [wn*64,+64) x m [wm*64,+64))
    __builtin_amdgcn_s_setprio(1);
#pragma unroll
    for (int i = 0; i < 4; ++i) {      // tok-tile
#pragma unroll
      for (int n = 0; n < 4; ++n) {    // m-tile
        floatx4 st = {0.0f, 0.0f, 0.0f, 0.0f};
        st = __builtin_amdgcn_mfma_f32_16x16x32_bf16(kf[i][0], qf[n][0], st, 0, 0, 0);
        st = __builtin_amdgcn_mfma_f32_16x16x32_bf16(kf[i][1], qf[n][1], st, 0, 0, 0);
        // lane holds S^T[tok = wn*64+i*16+q*4+r][m = wm*64+n*16+ln], r=0..3
        // Q pre-scaled by GEMM1 epilogue -> exp2 direct.
        bf16x4 pk;
#pragma unroll
        for (int r = 0; r < 4; ++r)
          pk[r] = (bf16_t)__builtin_amdgcn_exp2f(st[r]);
        const int m    = wm * 64 + n * 16 + ln;
        const int tok0 = wn * 64 + i * 16 + q * 4;
        *(bf16x4*)(lP + m * 128 + (((tok0 >> 3) ^ (m & 7)) << 3) + (tok0 & 7)) = pk;
      }
    }
    __builtin_amdgcn_s_setprio(0);

    // syncB: lP + lVT visible to all waves (also drains prefetches -- mostly
    // complete after the S^T phase above).
    __syncthreads();

    // ---- O += P * V ; rowsum += P * 1
    // m-split: wave owns m in [wave*32, +32), all 64 d. accS deduped.
    __builtin_amdgcn_s_setprio(1);
#pragma unroll
    for (int ks = 0; ks < 4; ++ks) {
      bf16x8 bv[4];
#pragma unroll
      for (int n = 0; n < 4; ++n) {
        const int d  = n * 16 + ln;
        const int cc = (ks * 4 + q) ^ (d & 7);
        bv[n] = *(const bf16x8*)(lVT + d * 128 + cc * 8);
      }
#pragma unroll
      for (int i = 0; i < 2; ++i) {
        const int m = wave * 32 + i * 16 + ln;
        const bf16x8 ap = *(const bf16x8*)(lP + m * 128 + (((ks * 4 + q) ^ (m & 7)) << 3));
#pragma unroll
        for (int n = 0; n < 4; ++n)
          accO[i][n] = __builtin_amdgcn_mfma_f32_16x16x32_bf16(ap, bv[n], accO[i][n], 0, 0, 0);
        accS[i] = __builtin_amdgcn_mfma_f32_16x16x32_bf16(ap, ones, accS[i], 0, 0, 0);
      }
    }
    __builtin_amdgcn_s_setprio(0);

    if (jt < 15) {
#pragma unroll
      for (int it = 0; it < 2; ++it) {
        vcur[it][0] = vnxt[it][0];
        vcur[it][1] = vnxt[it][1];
      }
    }
  }

  // ---- normalize and store O over the Q slot.
#pragma unroll
  for (int i = 0; i < 2; ++i) {
#pragma unroll
    for (int r = 0; r < 4; ++r) {
      const int row = wave * 32 + i * 16 + q * 4 + r;
      const float rcp = 1.0f / fmaxf(accS[i][r], 1e-20f);
#pragma unroll
      for (int n = 0; n < 4; ++n) {
        const int col = n * 16 + ln;
        Qbase[(size_t)row * 3072 + col] = (bf16_t)(accO[i][n][r] * rcp);
      }
    }
  }
}

// ---------------------------------------------------------------------------
extern "C" void kernel_launch(void* const* d_in, const int* in_sizes, int n_in,
                              void* d_out, int out_size, void* d_ws, size_t ws_size,
                              hipStream_t stream)
{
  const float* x     = (const float*)d_in[0];  // [4,2048,1024] fp32
  const float* w_qkv = (const float*)d_in[1];  // [3072,1024]   fp32
  const float* w_out = (const float*)d_in[2];  // [1024,1024]   fp32
  const float* b_out = (const float*)d_in[3];  // [1024]        fp32
  float* out = (float*)d_out;                  // [4,2048,1024] fp32

  // ws layout (75.5 MB total)
  bf16_t* qkv    = (bf16_t*)d_ws;                       // 8192*3072
  bf16_t* xb     = qkv    + (size_t)8192 * 3072;        // 8192*1024
  bf16_t* wqkvb  = xb     + (size_t)8192 * 1024;        // 3072*1024
  bf16_t* woutb  = wqkvb  + (size_t)3072 * 1024;        // 1024*1024

  // softmax scale (1/32) * log2(e), folded into Q by GEMM1's epilogue
  const float qs = 0.04508422f;

  // 0) pre-convert fp32 operands to bf16 (memory-bound, ~12 us)
  cvt_f32_bf16<<<dim3(4096), dim3(256), 0, stream>>>(x,     xb,    8192 * 1024 / 8);
  cvt_f32_bf16<<<dim3(1536), dim3(256), 0, stream>>>(w_qkv, wqkvb, 3072 * 1024 / 8);
  cvt_f32_bf16<<<dim3(512),  dim3(256), 0, stream>>>(w_out, woutb, 1024 * 1024 / 8);

  // 1) qkv = xb @ wqkvb^T   (Q cols pre-scaled in f32 by epilogue)
  gemm_bt<false, false, false><<<dim3(64 * 24), dim3(256), 0, stream>>>(
      xb, wqkvb, nullptr, qkv, 8192, 3072, 1024, 1024, 1024, qs);
  // 2) attention in-place: O overwrites the Q slot of qkv (bf16)
  attn_kernel<<<dim3(1024), dim3(256), 0, stream>>>(qkv);
  // 3) out = O @ woutb^T + b_out  (bf16 in, fp32 out; O strided at lda=3072)
  gemm_bt<false, false, true><<<dim3(64 * 8), dim3(256), 0, stream>>>(
      qkv, woutb, b_out, out, 8192, 1024, 1024, 3072, 0, 1.0f);
}

// Round 4
// 268.901 us; speedup vs baseline: 1.1247x; 1.0270x over previous
//
#include <hip/hip_runtime.h>

typedef __bf16 bf16_t;
typedef __bf16 bf16x2 __attribute__((ext_vector_type(2)));
typedef __bf16 bf16x4 __attribute__((ext_vector_type(4)));
typedef __bf16 bf16x8 __attribute__((ext_vector_type(8)));
typedef float floatx4 __attribute__((ext_vector_type(4)));

// async 16B/lane global->LDS (bf16 operands only). Dest = wave-uniform base + lane*16.
__device__ __forceinline__ void gll16(const void* g, void* l) {
  __builtin_amdgcn_global_load_lds(
      (const __attribute__((address_space(1))) void*)g,
      (__attribute__((address_space(3))) void*)l, 16, 0, 0);
}

__device__ __forceinline__ bf16x8 cvt8(const float4 a, const float4 b) {
  bf16x8 v;
  v[0] = (bf16_t)a.x; v[1] = (bf16_t)a.y; v[2] = (bf16_t)a.z; v[3] = (bf16_t)a.w;
  v[4] = (bf16_t)b.x; v[5] = (bf16_t)b.y; v[6] = (bf16_t)b.z; v[7] = (bf16_t)b.w;
  return v;
}

// ---------------------------------------------------------------------------
// fp32 -> bf16 for all three operands in ONE launch (saves 2 launch slots).
// blocks [0,4096) -> x, [4096,5632) -> w_qkv, [5632,6144) -> w_out.
// ---------------------------------------------------------------------------
__global__ __launch_bounds__(256)
void cvt_all(const float* __restrict__ x,  bf16_t* __restrict__ xb,
             const float* __restrict__ wq, bf16_t* __restrict__ wqb,
             const float* __restrict__ wo, bf16_t* __restrict__ wob)
{
  const int bid = blockIdx.x;
  const float* s;
  bf16_t* d;
  int i;
  if (bid < 4096)      { s = x;  d = xb;  i = bid * 256 + threadIdx.x; }
  else if (bid < 5632) { s = wq; d = wqb; i = (bid - 4096) * 256 + threadIdx.x; }
  else                 { s = wo; d = wob; i = (bid - 5632) * 256 + threadIdx.x; }
  const float4 a = ((const float4*)s)[2 * i];
  const float4 b = ((const float4*)s)[2 * i + 1];
  *(bf16x8*)(d + (size_t)i * 8) = cvt8(a, b);
}

// ---------------------------------------------------------------------------
// GEMM: C[M,Nf] = A[M,K] * W[Nf,K]^T (+bias), fp32 accum, bf16 MFMA.
// Round-13: BK 32 -> 64 (halves barrier/vmcnt-drain count: 32 -> 16 iters,
//           32 MFMA per drain), LDS 32 KiB, occupancy 2 -> 3 blocks/CU via
//           __launch_bounds__(256,3). Staging/swizzle = attn's proven
//           64-col r&7 XOR pattern. XCD map: mt-chunked (kept from r12).
// ---------------------------------------------------------------------------
template<bool C32>
__global__ __launch_bounds__(256, 3)
void gemm_bt(const bf16_t* __restrict__ Ab, const bf16_t* __restrict__ Wb,
             const float* __restrict__ bias, void* __restrict__ Cv,
             int M, int Nf, int K, int lda, int qcols, float qscale)
{
  __shared__ __align__(16) bf16_t lA[128 * 64];
  __shared__ __align__(16) bf16_t lB[128 * 64];

  const int tid  = threadIdx.x;
  const int wave = tid >> 6;
  const int lane = tid & 63;
  const int q    = lane >> 4;
  const int ln   = lane & 15;
  const int wm   = wave >> 1, wn = wave & 1;

  // XCD mapping: x = hw XCD (blockIdx%8). XCD x owns mt in [x*8, x*8+8),
  // iterating nt-major inside. Requires mtiles==64 (M==8192): holds here.
  const int x     = blockIdx.x & 7;
  const int local = blockIdx.x >> 3;
  const int mt = x * 8 + (local & 7);
  const int nt = local >> 3;
  const int m0 = mt << 7, n0 = nt << 7;

  floatx4 acc[4][4] = {};

  for (int k0 = 0; k0 < K; k0 += 64) {
    // stage A and W tiles [128 rows][64 cols], LDS chunk c holds global
    // chunk c ^ (r&7)  (same algebra as attn's Q/K staging).
#pragma unroll
    for (int t = 0; t < 4; ++t) {
      const int rbase = t * 32 + wave * 8;
      const int r  = rbase + (lane >> 3);
      const int gc = (lane & 7) ^ (r & 7);
      gll16(Ab + (size_t)(m0 + r) * lda + k0 + gc * 8, lA + rbase * 64);
      gll16(Wb + (size_t)(n0 + r) * K   + k0 + gc * 8, lB + rbase * 64);
    }
    __syncthreads();

    bf16x8 af[4][2], bfr[4][2];
#pragma unroll
    for (int i = 0; i < 4; ++i) {
      const int r = wm * 64 + i * 16 + ln;
#pragma unroll
      for (int kt = 0; kt < 2; ++kt) {
        const int c = (kt * 4 + q) ^ (r & 7);
        af[i][kt] = *(const bf16x8*)(lA + r * 64 + c * 8);
      }
    }
#pragma unroll
    for (int j = 0; j < 4; ++j) {
      const int r = wn * 64 + j * 16 + ln;
#pragma unroll
      for (int kt = 0; kt < 2; ++kt) {
        const int c = (kt * 4 + q) ^ (r & 7);
        bfr[j][kt] = *(const bf16x8*)(lB + r * 64 + c * 8);
      }
    }
#pragma unroll
    for (int i = 0; i < 4; ++i)
#pragma unroll
      for (int j = 0; j < 4; ++j)
#pragma unroll
        for (int kt = 0; kt < 2; ++kt)
          acc[i][j] = __builtin_amdgcn_mfma_f32_16x16x32_bf16(af[i][kt], bfr[j][kt], acc[i][j], 0, 0, 0);
    __syncthreads();
  }

  // epilogue: C/D layout col=lane&15, row=(lane>>4)*4+reg
#pragma unroll
  for (int j = 0; j < 4; ++j) {
    const int col = n0 + wn * 64 + j * 16 + ln;
    const float bv = bias ? bias[col] : 0.0f;
    const float sc = (col < qcols) ? qscale : 1.0f;
#pragma unroll
    for (int i = 0; i < 4; ++i) {
      const int row = m0 + wm * 64 + i * 16 + q * 4;
#pragma unroll
      for (int r = 0; r < 4; ++r) {
        const float val = acc[i][j][r] * sc + bv;
        if constexpr (C32)
          ((float*)Cv)[(size_t)(row + r) * Nf + col] = val;
        else
          ((bf16_t*)Cv)[(size_t)(row + r) * Nf + col] = (bf16_t)val;
      }
    }
  }
}

// ---------------------------------------------------------------------------
// Attention, in-place on bf16 qkv (Q pre-scaled by softmax scale * log2e).
// UNCHANGED from round 12 (passing, 98.4 us).
// ---------------------------------------------------------------------------
__global__ __launch_bounds__(256, 2)
void attn_kernel(bf16_t* __restrict__ qkv)
{
  __shared__ __align__(16) bf16_t lK[2][128 * 64]; // K tile dbuf [128 tok][64 d]
  __shared__ __align__(16) bf16_t lVT[64 * 128];   // V^T [64 d][128 tok], chunk^(d&7)
  __shared__ __align__(16) bf16_t lP[128 * 128];   // P [m][tok], chunk^(m&7); head = Q staging

  const int tid  = threadIdx.x;
  const int wave = tid >> 6;
  const int lane = tid & 63;
  const int q  = lane >> 4;
  const int ln = lane & 15;
  const int wm = wave >> 1, wn = wave & 1;

  // XCD swizzle: hw%8 = XCD; give each XCD 128 consecutive work-ids
  // (= all 16 q-tiles of 8 heads -> K/V working set 4MB = one L2).
  const int hw = blockIdx.x;
  const int w  = (hw & 7) * 128 + (hw >> 3);
  const int qt = w & 15;
  const int h  = (w >> 4) & 15;
  const int b  = w >> 8;

  bf16_t* Qbase = qkv + (size_t)(b * 2048 + qt * 128) * 3072 + h * 64;  // also O dest
  const bf16_t* Kbase = qkv + (size_t)(b * 2048) * 3072 + 1024 + h * 64;
  const bf16_t* Vbase = qkv + (size_t)(b * 2048) * 3072 + 2048 + h * 64;

  // ---- prologue: stage Q into lP head (flat [128][64], chunk^(r&7)) + K[0]
#pragma unroll
  for (int t = 0; t < 4; ++t) {
    const int rbase = t * 32 + wave * 8;
    const int r  = rbase + (lane >> 3);
    const int gc = (lane & 7) ^ (r & 7);
    gll16(Qbase + (size_t)r * 3072 + gc * 8, lP + rbase * 64);
    gll16(Kbase + (size_t)r * 3072 + gc * 8, lK[0] + rbase * 64);
  }
  __syncthreads();

  bf16x8 qf[4][2];  // Q[m][d] fragments; used as MFMA B-operand (Q^T[d][m])
#pragma unroll
  for (int i = 0; i < 4; ++i) {
    const int r = wm * 64 + i * 16 + ln;
#pragma unroll
    for (int kt = 0; kt < 2; ++kt) {
      const int c = (kt * 4 + q) ^ (r & 7);
      qf[i][kt] = *(const bf16x8*)(lP + r * 64 + c * 8);
    }
  }
  // (no barrier needed here: iter-0's top barrier orders qf reads vs lP reuse)

  // V[0] into regs (token pair 2*lane, 2*lane+1; d-chunks wave + it*4)
  bf16x8 vcur[2][2], vnxt[2][2];
#pragma unroll
  for (int it = 0; it < 2; ++it) {
    const bf16_t* src = Vbase + (size_t)(2 * lane) * 3072 + (wave + it * 4) * 8;
    vcur[it][0] = *(const bf16x8*)src;
    vcur[it][1] = *(const bf16x8*)(src + 3072);
  }

  floatx4 accO[2][4] = {};  // [m-tile i][d-tile n]
  floatx4 accS[2] = {};     // row sums via ones-column MFMA (deduped: 1x per m-row)

  bf16x8 ones;
#pragma unroll
  for (int j = 0; j < 8; ++j) ones[j] = (bf16_t)1.0f;

  for (int jt = 0; jt < 16; ++jt) {
    const bf16_t* lKc = lK[jt & 1];
    bf16_t*       lKn = lK[(jt & 1) ^ 1];

    // syncA: prev-iter PV reads of lVT/lP done; lK[cur] gll16 + vcur loads
    // (issued one phase ago) complete here via the barrier's vmcnt drain.
    __syncthreads();

    // scatter vcur -> lVT[d][tok], tok-chunk ch = (tok>>3)^(d&7)
#pragma unroll
    for (int it = 0; it < 2; ++it) {
      const int c = wave + it * 4;
#pragma unroll
      for (int j = 0; j < 8; ++j) {
        const int d  = c * 8 + j;
        const int ch = (lane >> 2) ^ (d & 7);
        bf16x2 pr;
        pr[0] = vcur[it][0][j];
        pr[1] = vcur[it][1][j];
        *(bf16x2*)(lVT + d * 128 + ch * 8 + ((2 * lane) & 7)) = pr;
      }
    }

    // K fragments from current buffer
    bf16x8 kf[4][2];
#pragma unroll
    for (int n = 0; n < 4; ++n) {
      const int r = wn * 64 + n * 16 + ln;
#pragma unroll
      for (int kt = 0; kt < 2; ++kt) {
        const int c = (kt * 4 + q) ^ (r & 7);
        kf[n][kt] = *(const bf16x8*)(lKc + r * 64 + c * 8);
      }
    }

    // ---- prefetch tile jt+1: K -> lK[nxt] (async DMA), V -> regs.
    // Drained at syncB, after the S^T phase -> latency mostly hidden.
    if (jt < 15) {
      const int j0n = (jt + 1) * 128;
#pragma unroll
      for (int t = 0; t < 4; ++t) {
        const int rbase = t * 32 + wave * 8;
        const int r  = rbase + (lane >> 3);
        const int gc = (lane & 7) ^ (r & 7);
        gll16(Kbase + (size_t)(j0n + r) * 3072 + gc * 8, lKn + rbase * 64);
      }
#pragma unroll
      for (int it = 0; it < 2; ++it) {
        const bf16_t* src = Vbase + (size_t)(j0n + 2 * lane) * 3072 + (wave + it * 4) * 8;
        vnxt[it][0] = *(const bf16x8*)src;
        vnxt[it][1] = *(const bf16x8*)(src + 3072);
      }
    }

    // ---- S^T = K Q^T  (wave: toks [wn*64,+64) x m [wm*64,+64))
    __builtin_amdgcn_s_setprio(1);
#pragma unroll
    for (int i = 0; i < 4; ++i) {      // tok-tile
#pragma unroll
      for (int n = 0; n < 4; ++n) {    // m-tile
        floatx4 st = {0.0f, 0.0f, 0.0f, 0.0f};
        st = __builtin_amdgcn_mfma_f32_16x16x32_bf16(kf[i][0], qf[n][0], st, 0, 0, 0);
        st = __builtin_amdgcn_mfma_f32_16x16x32_bf16(kf[i][1], qf[n][1], st, 0, 0, 0);
        // lane holds S^T[tok = wn*64+i*16+q*4+r][m = wm*64+n*16+ln], r=0..3
        // Q pre-scaled by GEMM1 epilogue -> exp2 direct.
        bf16x4 pk;
#pragma unroll
        for (int r = 0; r < 4; ++r)
          pk[r] = (bf16_t)__builtin_amdgcn_exp2f(st[r]);
        const int m    = wm * 64 + n * 16 + ln;
        const int tok0 = wn * 64 + i * 16 + q * 4;
        *(bf16x4*)(lP + m * 128 + (((tok0 >> 3) ^ (m & 7)) << 3) + (tok0 & 7)) = pk;
      }
    }
    __builtin_amdgcn_s_setprio(0);

    // syncB: lP + lVT visible to all waves (also drains prefetches -- mostly
    // complete after the S^T phase above).
    __syncthreads();

    // ---- O += P * V ; rowsum += P * 1
    // m-split: wave owns m in [wave*32, +32), all 64 d. accS deduped.
    __builtin_amdgcn_s_setprio(1);
#pragma unroll
    for (int ks = 0; ks < 4; ++ks) {
      bf16x8 bv[4];
#pragma unroll
      for (int n = 0; n < 4; ++n) {
        const int d  = n * 16 + ln;
        const int cc = (ks * 4 + q) ^ (d & 7);
        bv[n] = *(const bf16x8*)(lVT + d * 128 + cc * 8);
      }
#pragma unroll
      for (int i = 0; i < 2; ++i) {
        const int m = wave * 32 + i * 16 + ln;
        const bf16x8 ap = *(const bf16x8*)(lP + m * 128 + (((ks * 4 + q) ^ (m & 7)) << 3));
#pragma unroll
        for (int n = 0; n < 4; ++n)
          accO[i][n] = __builtin_amdgcn_mfma_f32_16x16x32_bf16(ap, bv[n], accO[i][n], 0, 0, 0);
        accS[i] = __builtin_amdgcn_mfma_f32_16x16x32_bf16(ap, ones, accS[i], 0, 0, 0);
      }
    }
    __builtin_amdgcn_s_setprio(0);

    if (jt < 15) {
#pragma unroll
      for (int it = 0; it < 2; ++it) {
        vcur[it][0] = vnxt[it][0];
        vcur[it][1] = vnxt[it][1];
      }
    }
  }

  // ---- normalize and store O over the Q slot.
#pragma unroll
  for (int i = 0; i < 2; ++i) {
#pragma unroll
    for (int r = 0; r < 4; ++r) {
      const int row = wave * 32 + i * 16 + q * 4 + r;
      const float rcp = 1.0f / fmaxf(accS[i][r], 1e-20f);
#pragma unroll
      for (int n = 0; n < 4; ++n) {
        const int col = n * 16 + ln;
        Qbase[(size_t)row * 3072 + col] = (bf16_t)(accO[i][n][r] * rcp);
      }
    }
  }
}

// ---------------------------------------------------------------------------
extern "C" void kernel_launch(void* const* d_in, const int* in_sizes, int n_in,
                              void* d_out, int out_size, void* d_ws, size_t ws_size,
                              hipStream_t stream)
{
  const float* x     = (const float*)d_in[0];  // [4,2048,1024] fp32
  const float* w_qkv = (const float*)d_in[1];  // [3072,1024]   fp32
  const float* w_out = (const float*)d_in[2];  // [1024,1024]   fp32
  const float* b_out = (const float*)d_in[3];  // [1024]        fp32
  float* out = (float*)d_out;                  // [4,2048,1024] fp32

  // ws layout (75.5 MB total)
  bf16_t* qkv    = (bf16_t*)d_ws;                       // 8192*3072
  bf16_t* xb     = qkv    + (size_t)8192 * 3072;        // 8192*1024
  bf16_t* wqkvb  = xb     + (size_t)8192 * 1024;        // 3072*1024
  bf16_t* woutb  = wqkvb  + (size_t)3072 * 1024;        // 1024*1024

  // softmax scale (1/32) * log2(e), folded into Q by GEMM1's epilogue
  const float qs = 0.04508422f;

  // 0) pre-convert all fp32 operands to bf16 in one launch
  cvt_all<<<dim3(6144), dim3(256), 0, stream>>>(x, xb, w_qkv, wqkvb, w_out, woutb);

  // 1) qkv = xb @ wqkvb^T   (Q cols pre-scaled in f32 by epilogue)
  gemm_bt<false><<<dim3(64 * 24), dim3(256), 0, stream>>>(
      xb, wqkvb, nullptr, qkv, 8192, 3072, 1024, 1024, 1024, qs);
  // 2) attention in-place: O overwrites the Q slot of qkv (bf16)
  attn_kernel<<<dim3(1024), dim3(256), 0, stream>>>(qkv);
  // 3) out = O @ woutb^T + b_out  (bf16 in, fp32 out; O strided at lda=3072)
  gemm_bt<true><<<dim3(64 * 8), dim3(256), 0, stream>>>(
      qkv, woutb, b_out, out, 8192, 1024, 1024, 3072, 0, 1.0f);
}

// Round 7
// 262.474 us; speedup vs baseline: 1.1523x; 1.0245x over previous
//
#include <hip/hip_runtime.h>

typedef __bf16 bf16_t;
typedef __bf16 bf16x2 __attribute__((ext_vector_type(2)));
typedef __bf16 bf16x4 __attribute__((ext_vector_type(4)));
typedef __bf16 bf16x8 __attribute__((ext_vector_type(8)));
typedef float floatx4 __attribute__((ext_vector_type(4)));

// async 16B/lane global->LDS (bf16 operands only). Dest = wave-uniform base + lane*16.
__device__ __forceinline__ void gll16(const void* g, void* l) {
  __builtin_amdgcn_global_load_lds(
      (const __attribute__((address_space(1))) void*)g,
      (__attribute__((address_space(3))) void*)l, 16, 0, 0);
}

// explicit LDS-DMA drain: gll16 completion is tracked by vmcnt only; with no
// register global-loads in the kernel, nothing dependency-driven ever waits
// on it, so the drain before each barrier must be explicit (T3 template).
__device__ __forceinline__ void drain_vmcnt() {
  asm volatile("s_waitcnt vmcnt(0)" ::: "memory");
  __builtin_amdgcn_sched_barrier(0);
}

__device__ __forceinline__ bf16x8 cvt8(const float4 a, const float4 b) {
  bf16x8 v;
  v[0] = (bf16_t)a.x; v[1] = (bf16_t)a.y; v[2] = (bf16_t)a.z; v[3] = (bf16_t)a.w;
  v[4] = (bf16_t)b.x; v[5] = (bf16_t)b.y; v[6] = (bf16_t)b.z; v[7] = (bf16_t)b.w;
  return v;
}

// ---------------------------------------------------------------------------
// fp32 -> bf16 for all three operands in ONE launch.
// blocks [0,4096) -> x, [4096,5632) -> w_qkv, [5632,6144) -> w_out.
// ---------------------------------------------------------------------------
__global__ __launch_bounds__(256)
void cvt_all(const float* __restrict__ x,  bf16_t* __restrict__ xb,
             const float* __restrict__ wq, bf16_t* __restrict__ wqb,
             const float* __restrict__ wo, bf16_t* __restrict__ wob)
{
  const int bid = blockIdx.x;
  const float* s;
  bf16_t* d;
  int i;
  if (bid < 4096)      { s = x;  d = xb;  i = bid * 256 + threadIdx.x; }
  else if (bid < 5632) { s = wq; d = wqb; i = (bid - 4096) * 256 + threadIdx.x; }
  else                 { s = wo; d = wob; i = (bid - 5632) * 256 + threadIdx.x; }
  const float4 a = ((const float4*)s)[2 * i];
  const float4 b = ((const float4*)s)[2 * i + 1];
  *(bf16x8*)(d + (size_t)i * 8) = cvt8(a, b);
}

// ---------------------------------------------------------------------------
// GEMM: C[M,Nf] = A[M,K] * W[Nf,K]^T (+bias), fp32 accum, bf16 MFMA.
// Round-16: rounds 5/6 failed from a MACRO-CAPTURE bug (the STAGE macro's
//   inner `for (int t...)` shadowed the outer k-loop's `t` inside the K0
//   argument -> every iteration staged tiles 1..4 per row-group; bit-identical
//   absmax across two builds was the tell). Fix: staging is a lambda with a
//   uniquely-named loop var. Pipeline structure unchanged (2-phase dbuf):
//   STAGE(t+1) -> ds_read/MFMA tile t -> vmcnt(0) drain -> barrier.
//   BK=64, 128x128 tile, mt-chunked XCD map, setprio around MFMA cluster.
// ---------------------------------------------------------------------------
template<bool C32>
__global__ __launch_bounds__(256, 2)
void gemm_bt(const bf16_t* __restrict__ Ab, const bf16_t* __restrict__ Wb,
             const float* __restrict__ bias, void* __restrict__ Cv,
             int M, int Nf, int K, int lda, int qcols, float qscale)
{
  __shared__ __align__(16) bf16_t lA[2][128 * 64];
  __shared__ __align__(16) bf16_t lB[2][128 * 64];

  const int tid  = threadIdx.x;
  const int wave = tid >> 6;
  const int lane = tid & 63;
  const int q    = lane >> 4;
  const int ln   = lane & 15;
  const int wm   = wave >> 1, wn = wave & 1;

  // XCD mapping: x = hw XCD (blockIdx%8). XCD x owns mt in [x*8, x*8+8),
  // iterating nt-major inside. Requires mtiles==64 (M==8192): holds here.
  const int x     = blockIdx.x & 7;
  const int local = blockIdx.x >> 3;
  const int mt = x * 8 + (local & 7);
  const int nt = local >> 3;
  const int m0 = mt << 7, n0 = nt << 7;

  // staging addresses (LDS chunk c holds global chunk c ^ (r&7))
  const int srb = (lane >> 3);          // sub-row within 8-row group
  const int sgc = (lane & 7);           // global chunk base (pre-XOR)

  floatx4 acc[4][4] = {};

  const int kiters = K >> 6;

  // staging as a lambda: no macro token capture; k0s is evaluated at the
  // CALL site, inner loop var is tt.
  auto stage = [&](int buf, int k0s) {
#pragma unroll
    for (int tt = 0; tt < 4; ++tt) {
      const int rbase = tt * 32 + wave * 8;
      const int r  = rbase + srb;
      const int gc = sgc ^ (r & 7);
      gll16(Ab + (size_t)(m0 + r) * lda + k0s + gc * 8, lA[buf] + rbase * 64);
      gll16(Wb + (size_t)(n0 + r) * K   + k0s + gc * 8, lB[buf] + rbase * 64);
    }
  };

  stage(0, 0);
  drain_vmcnt();
  __syncthreads();

  int cur = 0;
  for (int t = 0; t < kiters; ++t) {
    // issue next tile's staging FIRST (overlaps with this tile's compute)
    if (t + 1 < kiters) stage(cur ^ 1, (t + 1) << 6);

    bf16x8 af[4][2], bfr[4][2];
#pragma unroll
    for (int i = 0; i < 4; ++i) {
      const int r = wm * 64 + i * 16 + ln;
#pragma unroll
      for (int kt = 0; kt < 2; ++kt) {
        const int c = (kt * 4 + q) ^ (r & 7);
        af[i][kt] = *(const bf16x8*)(lA[cur] + r * 64 + c * 8);
      }
    }
#pragma unroll
    for (int j = 0; j < 4; ++j) {
      const int r = wn * 64 + j * 16 + ln;
#pragma unroll
      for (int kt = 0; kt < 2; ++kt) {
        const int c = (kt * 4 + q) ^ (r & 7);
        bfr[j][kt] = *(const bf16x8*)(lB[cur] + r * 64 + c * 8);
      }
    }
    __builtin_amdgcn_s_setprio(1);
#pragma unroll
    for (int i = 0; i < 4; ++i)
#pragma unroll
      for (int j = 0; j < 4; ++j)
#pragma unroll
        for (int kt = 0; kt < 2; ++kt)
          acc[i][j] = __builtin_amdgcn_mfma_f32_16x16x32_bf16(af[i][kt], bfr[j][kt], acc[i][j], 0, 0, 0);
    __builtin_amdgcn_s_setprio(0);

    // explicit drain: next tile's DMA landed; then barrier closes this
    // tile's LDS reads for all waves.
    drain_vmcnt();
    __syncthreads();
    cur ^= 1;
  }

  // epilogue: C/D layout col=lane&15, row=(lane>>4)*4+reg
#pragma unroll
  for (int j = 0; j < 4; ++j) {
    const int col = n0 + wn * 64 + j * 16 + ln;
    const float bv = bias ? bias[col] : 0.0f;
    const float sc = (col < qcols) ? qscale : 1.0f;
#pragma unroll
    for (int i = 0; i < 4; ++i) {
      const int row = m0 + wm * 64 + i * 16 + q * 4;
#pragma unroll
      for (int r = 0; r < 4; ++r) {
        const float val = acc[i][j][r] * sc + bv;
        if constexpr (C32)
          ((float*)Cv)[(size_t)(row + r) * Nf + col] = val;
        else
          ((bf16_t*)Cv)[(size_t)(row + r) * Nf + col] = (bf16_t)val;
      }
    }
  }
}

// ---------------------------------------------------------------------------
// Attention, in-place on bf16 qkv (Q pre-scaled by softmax scale * log2e).
// UNCHANGED from round 12 (passing, ~99 us).
// ---------------------------------------------------------------------------
__global__ __launch_bounds__(256, 2)
void attn_kernel(bf16_t* __restrict__ qkv)
{
  __shared__ __align__(16) bf16_t lK[2][128 * 64]; // K tile dbuf [128 tok][64 d]
  __shared__ __align__(16) bf16_t lVT[64 * 128];   // V^T [64 d][128 tok], chunk^(d&7)
  __shared__ __align__(16) bf16_t lP[128 * 128];   // P [m][tok], chunk^(m&7); head = Q staging

  const int tid  = threadIdx.x;
  const int wave = tid >> 6;
  const int lane = tid & 63;
  const int q  = lane >> 4;
  const int ln = lane & 15;
  const int wm = wave >> 1, wn = wave & 1;

  // XCD swizzle: hw%8 = XCD; give each XCD 128 consecutive work-ids
  // (= all 16 q-tiles of 8 heads -> K/V working set 4MB = one L2).
  const int hw = blockIdx.x;
  const int w  = (hw & 7) * 128 + (hw >> 3);
  const int qt = w & 15;
  const int h  = (w >> 4) & 15;
  const int b  = w >> 8;

  bf16_t* Qbase = qkv + (size_t)(b * 2048 + qt * 128) * 3072 + h * 64;  // also O dest
  const bf16_t* Kbase = qkv + (size_t)(b * 2048) * 3072 + 1024 + h * 64;
  const bf16_t* Vbase = qkv + (size_t)(b * 2048) * 3072 + 2048 + h * 64;

  // ---- prologue: stage Q into lP head (flat [128][64], chunk^(r&7)) + K[0]
#pragma unroll
  for (int t = 0; t < 4; ++t) {
    const int rbase = t * 32 + wave * 8;
    const int r  = rbase + (lane >> 3);
    const int gc = (lane & 7) ^ (r & 7);
    gll16(Qbase + (size_t)r * 3072 + gc * 8, lP + rbase * 64);
    gll16(Kbase + (size_t)r * 3072 + gc * 8, lK[0] + rbase * 64);
  }
  __syncthreads();

  bf16x8 qf[4][2];  // Q[m][d] fragments; used as MFMA B-operand (Q^T[d][m])
#pragma unroll
  for (int i = 0; i < 4; ++i) {
    const int r = wm * 64 + i * 16 + ln;
#pragma unroll
    for (int kt = 0; kt < 2; ++kt) {
      const int c = (kt * 4 + q) ^ (r & 7);
      qf[i][kt] = *(const bf16x8*)(lP + r * 64 + c * 8);
    }
  }
  // (no barrier needed here: iter-0's top barrier orders qf reads vs lP reuse)

  // V[0] into regs (token pair 2*lane, 2*lane+1; d-chunks wave + it*4)
  bf16x8 vcur[2][2], vnxt[2][2];
#pragma unroll
  for (int it = 0; it < 2; ++it) {
    const bf16_t* src = Vbase + (size_t)(2 * lane) * 3072 + (wave + it * 4) * 8;
    vcur[it][0] = *(const bf16x8*)src;
    vcur[it][1] = *(const bf16x8*)(src + 3072);
  }

  floatx4 accO[2][4] = {};  // [m-tile i][d-tile n]
  floatx4 accS[2] = {};     // row sums via ones-column MFMA (deduped: 1x per m-row)

  bf16x8 ones;
#pragma unroll
  for (int j = 0; j < 8; ++j) ones[j] = (bf16_t)1.0f;

  for (int jt = 0; jt < 16; ++jt) {
    const bf16_t* lKc = lK[jt & 1];
    bf16_t*       lKn = lK[(jt & 1) ^ 1];

    // syncA: prev-iter PV reads of lVT/lP done; lK[cur] gll16 + vcur loads
    // (issued one phase ago) complete here via the in-order vmcnt chain
    // (vcur register loads were issued after the K DMAs).
    __syncthreads();

    // scatter vcur -> lVT[d][tok], tok-chunk ch = (tok>>3)^(d&7)
#pragma unroll
    for (int it = 0; it < 2; ++it) {
      const int c = wave + it * 4;
#pragma unroll
      for (int j = 0; j < 8; ++j) {
        const int d  = c * 8 + j;
        const int ch = (lane >> 2) ^ (d & 7);
        bf16x2 pr;
        pr[0] = vcur[it][0][j];
        pr[1] = vcur[it][1][j];
        *(bf16x2*)(lVT + d * 128 + ch * 8 + ((2 * lane) & 7)) = pr;
      }
    }

    // K fragments from current buffer
    bf16x8 kf[4][2];
#pragma unroll
    for (int n = 0; n < 4; ++n) {
      const int r = wn * 64 + n * 16 + ln;
#pragma unroll
      for (int kt = 0; kt < 2; ++kt) {
        const int c = (kt * 4 + q) ^ (r & 7);
        kf[n][kt] = *(const bf16x8*)(lKc + r * 64 + c * 8);
      }
    }

    // ---- prefetch tile jt+1: K -> lK[nxt] (async DMA), V -> regs.
    // Drained at syncB, after the S^T phase -> latency mostly hidden.
    if (jt < 15) {
      const int j0n = (jt + 1) * 128;
#pragma unroll
      for (int t = 0; t < 4; ++t) {
        const int rbase = t * 32 + wave * 8;
        const int r  = rbase + (lane >> 3);
        const int gc = (lane & 7) ^ (r & 7);
        gll16(Kbase + (size_t)(j0n + r) * 3072 + gc * 8, lKn + rbase * 64);
      }
#pragma unroll
      for (int it = 0; it < 2; ++it) {
        const bf16_t* src = Vbase + (size_t)(j0n + 2 * lane) * 3072 + (wave + it * 4) * 8;
        vnxt[it][0] = *(const bf16x8*)src;
        vnxt[it][1] = *(const bf16x8*)(src + 3072);
      }
    }

    // ---- S^T = K Q^T  (wave: toks [wn*64,+64) x m [wm*64,+64))
    __builtin_amdgcn_s_setprio(1);
#pragma unroll
    for (int i = 0; i < 4; ++i) {      // tok-tile
#pragma unroll
      for (int n = 0; n < 4; ++n) {    // m-tile
        floatx4 st = {0.0f, 0.0f, 0.0f, 0.0f};
        st = __builtin_amdgcn_mfma_f32_16x16x32_bf16(kf[i][0], qf[n][0], st, 0, 0, 0);
        st = __builtin_amdgcn_mfma_f32_16x16x32_bf16(kf[i][1], qf[n][1], st, 0, 0, 0);
        // lane holds S^T[tok = wn*64+i*16+q*4+r][m = wm*64+n*16+ln], r=0..3
        // Q pre-scaled by GEMM1 epilogue -> exp2 direct.
        bf16x4 pk;
#pragma unroll
        for (int r = 0; r < 4; ++r)
          pk[r] = (bf16_t)__builtin_amdgcn_exp2f(st[r]);
        const int m    = wm * 64 + n * 16 + ln;
        const int tok0 = wn * 64 + i * 16 + q * 4;
        *(bf16x4*)(lP + m * 128 + (((tok0 >> 3) ^ (m & 7)) << 3) + (tok0 & 7)) = pk;
      }
    }
    __builtin_amdgcn_s_setprio(0);

    // syncB: lP + lVT visible to all waves (also drains prefetches -- mostly
    // complete after the S^T phase above).
    __syncthreads();

    // ---- O += P * V ; rowsum += P * 1
    // m-split: wave owns m in [wave*32, +32), all 64 d. accS deduped.
    __builtin_amdgcn_s_setprio(1);
#pragma unroll
    for (int ks = 0; ks < 4; ++ks) {
      bf16x8 bv[4];
#pragma unroll
      for (int n = 0; n < 4; ++n) {
        const int d  = n * 16 + ln;
        const int cc = (ks * 4 + q) ^ (d & 7);
        bv[n] = *(const bf16x8*)(lVT + d * 128 + cc * 8);
      }
#pragma unroll
      for (int i = 0; i < 2; ++i) {
        const int m = wave * 32 + i * 16 + ln;
        const bf16x8 ap = *(const bf16x8*)(lP + m * 128 + (((ks * 4 + q) ^ (m & 7)) << 3));
#pragma unroll
        for (int n = 0; n < 4; ++n)
          accO[i][n] = __builtin_amdgcn_mfma_f32_16x16x32_bf16(ap, bv[n], accO[i][n], 0, 0, 0);
        accS[i] = __builtin_amdgcn_mfma_f32_16x16x32_bf16(ap, ones, accS[i], 0, 0, 0);
      }
    }
    __builtin_amdgcn_s_setprio(0);

    if (jt < 15) {
#pragma unroll
      for (int it = 0; it < 2; ++it) {
        vcur[it][0] = vnxt[it][0];
        vcur[it][1] = vnxt[it][1];
      }
    }
  }

  // ---- normalize and store O over the Q slot.
#pragma unroll
  for (int i = 0; i < 2; ++i) {
#pragma unroll
    for (int r = 0; r < 4; ++r) {
      const int row = wave * 32 + i * 16 + q * 4 + r;
      const float rcp = 1.0f / fmaxf(accS[i][r], 1e-20f);
#pragma unroll
      for (int n = 0; n < 4; ++n) {
        const int col = n * 16 + ln;
        Qbase[(size_t)row * 3072 + col] = (bf16_t)(accO[i][n][r] * rcp);
      }
    }
  }
}

// ---------------------------------------------------------------------------
extern "C" void kernel_launch(void* const* d_in, const int* in_sizes, int n_in,
                              void* d_out, int out_size, void* d_ws, size_t ws_size,
                              hipStream_t stream)
{
  const float* x     = (const float*)d_in[0];  // [4,2048,1024] fp32
  const float* w_qkv = (const float*)d_in[1];  // [3072,1024]   fp32
  const float* w_out = (const float*)d_in[2];  // [1024,1024]   fp32
  const float* b_out = (const float*)d_in[3];  // [1024]        fp32
  float* out = (float*)d_out;                  // [4,2048,1024] fp32

  // ws layout (75.5 MB total)
  bf16_t* qkv    = (bf16_t*)d_ws;                       // 8192*3072
  bf16_t* xb     = qkv    + (size_t)8192 * 3072;        // 8192*1024
  bf16_t* wqkvb  = xb     + (size_t)8192 * 1024;        // 3072*1024
  bf16_t* woutb  = wqkvb  + (size_t)3072 * 1024;        // 1024*1024

  // softmax scale (1/32) * log2(e), folded into Q by GEMM1's epilogue
  const float qs = 0.04508422f;

  // 0) pre-convert all fp32 operands to bf16 in one launch
  cvt_all<<<dim3(6144), dim3(256), 0, stream>>>(x, xb, w_qkv, wqkvb, w_out, woutb);

  // 1) qkv = xb @ wqkvb^T   (Q cols pre-scaled in f32 by epilogue)
  gemm_bt<false><<<dim3(64 * 24), dim3(256), 0, stream>>>(
      xb, wqkvb, nullptr, qkv, 8192, 3072, 1024, 1024, 1024, qs);
  // 2) attention in-place: O overwrites the Q slot of qkv (bf16)
  attn_kernel<<<dim3(1024), dim3(256), 0, stream>>>(qkv);
  // 3) out = O @ woutb^T + b_out  (bf16 in, fp32 out; O strided at lda=3072)
  gemm_bt<true><<<dim3(64 * 8), dim3(256), 0, stream>>>(
      qkv, woutb, b_out, out, 8192, 1024, 1024, 3072, 0, 1.0f);
}